// Round 4
// baseline (3736.329 us; speedup 1.0000x reference)
//
#include <hip/hip_runtime.h>
#include <hip/hip_bf16.h>

#define BB   2048
#define SS   256
#define NTOK (BB*SS)
#define FIN  3
#define CND  4
#define EMB  4
#define HID  64
#define NC   256
#define TPB  256

// ---------------- encoder LDS layout (float offsets, float4-aligned) --------
#define E_EW1 0        // 448
#define E_EB1 448      // 64
#define E_EW2 512      // 4096
#define E_EB2 4608     // 64
#define E_EW3 4672     // 256
#define E_EB3 4928     // 4
#define E_CB  4932     // 1024 (4932*4B % 16 == 0)
#define E_CC  5956     // 256
#define E_SZ  6212     // 24848 B -> 6 blocks/CU

// ---------------- decoder LDS layout ----------------------------------------
#define D_DW1 0        // 512
#define D_DB1 512      // 64
#define D_DW2 576      // 4096
#define D_DB2 4672     // 64
#define D_DW3 4736     // 192
#define D_DB3 4928     // 3 (pad to 4932)
#define D_CB  4932     // 1024
#define D_SZ  5956     // 23824 B -> 6 blocks/CU

__global__ __launch_bounds__(TPB, 6) void enc_kernel(
        const float* __restrict__ x, const float* __restrict__ mask,
        const float* __restrict__ cond,
        const float* __restrict__ ew1, const float* __restrict__ eb1,
        const float* __restrict__ ew2, const float* __restrict__ eb2,
        const float* __restrict__ ew3, const float* __restrict__ eb3,
        const float* __restrict__ cb,
        float* __restrict__ out, float* __restrict__ loss_ws) {
    __shared__ float smem[E_SZ];
    const int tid = threadIdx.x;

    for (int i = tid; i < (FIN+CND)*HID; i += TPB) smem[E_EW1+i] = ew1[i];
    for (int i = tid; i < HID;           i += TPB) smem[E_EB1+i] = eb1[i];
    for (int i = tid; i < HID*HID;       i += TPB) smem[E_EW2+i] = ew2[i];
    for (int i = tid; i < HID;           i += TPB) smem[E_EB2+i] = eb2[i];
    for (int i = tid; i < HID*EMB;       i += TPB) smem[E_EW3+i] = ew3[i];
    for (int i = tid; i < EMB;           i += TPB) smem[E_EB3+i] = eb3[i];
    for (int i = tid; i < NC*EMB;        i += TPB) smem[E_CB +i] = cb[i];
    if (tid < NC) {   // cc from GLOBAL cb (no barrier dependency)
        float c0 = cb[tid*EMB+0], c1 = cb[tid*EMB+1];
        float c2 = cb[tid*EMB+2], c3 = cb[tid*EMB+3];
        smem[E_CC+tid] = ((c0*c0 + c1*c1) + c2*c2) + c3*c3;  // validated order
    }
    __syncthreads();

    const int n  = blockIdx.x * TPB + tid;
    const int bu = n >> 8;
    const float m = mask[n];

    float cnd[CND];
    #pragma unroll
    for (int i = 0; i < CND; i++) cnd[i] = cond[bu*CND + i];

    float xin[FIN + CND];
    #pragma unroll
    for (int i = 0; i < FIN; i++) xin[i] = x[n*FIN + i] * m;
    #pragma unroll
    for (int i = 0; i < CND; i++) xin[FIN + i] = cnd[i] * m;

    // ---- encoder L1: 7 -> 64, relu (validated tree) ----
    float h1[HID];
    #pragma unroll
    for (int j = 0; j < HID; j++) {
        float a = xin[0] * smem[E_EW1 + j];
        #pragma unroll
        for (int i = 1; i < FIN+CND; i++) a = fmaf(xin[i], smem[E_EW1 + i*HID + j], a);
        a += smem[E_EB1 + j];
        h1[j] = fmaxf(a, 0.0f);
    }

    // ---- encoder L2 (relu) fused with L3 fold (validated tree) ----
    float z0 = 0.f, z1 = 0.f, z2 = 0.f, z3 = 0.f;
    for (int jt = 0; jt < 16; jt++) {
        float a0 = 0.f, a1 = 0.f, a2 = 0.f, a3 = 0.f;
        #pragma unroll
        for (int k = 0; k < HID; k++) {
            float4 w = *(const float4*)&smem[E_EW2 + k*HID + jt*4];
            a0 = fmaf(h1[k], w.x, a0);
            a1 = fmaf(h1[k], w.y, a1);
            a2 = fmaf(h1[k], w.z, a2);
            a3 = fmaf(h1[k], w.w, a3);
        }
        float4 b = *(const float4*)&smem[E_EB2 + jt*4];
        float t0 = fmaxf(a0 + b.x, 0.0f);
        float t1 = fmaxf(a1 + b.y, 0.0f);
        float t2 = fmaxf(a2 + b.z, 0.0f);
        float t3 = fmaxf(a3 + b.w, 0.0f);
        float4 w0 = *(const float4*)&smem[E_EW3 + (jt*4+0)*EMB];
        z0 = fmaf(t0, w0.x, z0); z1 = fmaf(t0, w0.y, z1);
        z2 = fmaf(t0, w0.z, z2); z3 = fmaf(t0, w0.w, z3);
        float4 w1 = *(const float4*)&smem[E_EW3 + (jt*4+1)*EMB];
        z0 = fmaf(t1, w1.x, z0); z1 = fmaf(t1, w1.y, z1);
        z2 = fmaf(t1, w1.z, z2); z3 = fmaf(t1, w1.w, z3);
        float4 w2 = *(const float4*)&smem[E_EW3 + (jt*4+2)*EMB];
        z0 = fmaf(t2, w2.x, z0); z1 = fmaf(t2, w2.y, z1);
        z2 = fmaf(t2, w2.z, z2); z3 = fmaf(t2, w2.w, z3);
        float4 w3 = *(const float4*)&smem[E_EW3 + (jt*4+3)*EMB];
        z0 = fmaf(t3, w3.x, z0); z1 = fmaf(t3, w3.y, z1);
        z2 = fmaf(t3, w3.z, z2); z3 = fmaf(t3, w3.w, z3);
    }
    z0 += smem[E_EB3+0]; z1 += smem[E_EB3+1];
    z2 += smem[E_EB3+2]; z3 += smem[E_EB3+3];

    // ---- VQ argmin (validated tree; strict < = np first-min) ----
    const float zz = ((z0*z0 + z1*z1) + z2*z2) + z3*z3;
    float best = 3.4e38f;
    int   bi   = 0;
    #pragma unroll 4
    for (int ci = 0; ci < NC; ci++) {
        float4 c = *(const float4*)&smem[E_CB + ci*EMB];
        float dot = z0 * c.x;
        dot = fmaf(z1, c.y, dot);
        dot = fmaf(z2, c.z, dot);
        dot = fmaf(z3, c.w, dot);
        float d = (zz - 2.0f*dot) + smem[E_CC + ci];
        if (d < best) { best = d; bi = ci; }
    }
    float4 q = *(const float4*)&smem[E_CB + bi*EMB];

    // ---- vq loss partial ----
    float e0 = z0-q.x, e1 = z1-q.y, e2 = z2-q.z, e3 = z3-q.w;
    float sq = ((e0*e0 + e1*e1) + e2*e2) + e3*e3;
    #pragma unroll
    for (int off = 32; off > 0; off >>= 1) sq += __shfl_down(sq, off, 64);
    if ((tid & 63) == 0) atomicAdd(loss_ws, sq);

    // idx out; decoder rereads it to recover q from its own cb copy
    out[NTOK*FIN + 1 + n] = (float)bi;
}

__global__ __launch_bounds__(TPB, 6) void dec_kernel(
        const float* __restrict__ mask, const float* __restrict__ cond,
        const float* __restrict__ dw1, const float* __restrict__ db1,
        const float* __restrict__ dw2, const float* __restrict__ db2,
        const float* __restrict__ dw3, const float* __restrict__ db3,
        const float* __restrict__ cb,
        float* __restrict__ out) {
    __shared__ float smem[D_SZ];
    const int tid = threadIdx.x;

    for (int i = tid; i < (EMB+CND)*HID; i += TPB) smem[D_DW1+i] = dw1[i];
    for (int i = tid; i < HID;           i += TPB) smem[D_DB1+i] = db1[i];
    for (int i = tid; i < HID*HID;       i += TPB) smem[D_DW2+i] = dw2[i];
    for (int i = tid; i < HID;           i += TPB) smem[D_DB2+i] = db2[i];
    for (int i = tid; i < HID*FIN;       i += TPB) smem[D_DW3+i] = dw3[i];
    for (int i = tid; i < FIN;           i += TPB) smem[D_DB3+i] = db3[i];
    for (int i = tid; i < NC*EMB;        i += TPB) smem[D_CB +i] = cb[i];
    __syncthreads();

    const int n  = blockIdx.x * TPB + tid;
    const int bu = n >> 8;
    const float m = mask[n];

    float cnd[CND];
    #pragma unroll
    for (int i = 0; i < CND; i++) cnd[i] = cond[bu*CND + i];

    const int bi = (int)out[NTOK*FIN + 1 + n];   // exact small-int roundtrip
    float4 q = *(const float4*)&smem[D_CB + bi*EMB];

    // ---- decoder L1: 8 -> 64, relu (validated tree) ----
    float zd[EMB + CND];
    zd[0] = q.x*m; zd[1] = q.y*m; zd[2] = q.z*m; zd[3] = q.w*m;
    #pragma unroll
    for (int i = 0; i < CND; i++) zd[EMB + i] = cnd[i] * m;

    float hd[HID];
    #pragma unroll
    for (int j = 0; j < HID; j++) {
        float a = zd[0] * smem[D_DW1 + j];
        #pragma unroll
        for (int i = 1; i < EMB+CND; i++) a = fmaf(zd[i], smem[D_DW1 + i*HID + j], a);
        a += smem[D_DB1 + j];
        hd[j] = fmaxf(a, 0.0f);
    }

    // ---- decoder L2 (relu) fused with L3 (validated tree) ----
    float r0 = 0.f, r1 = 0.f, r2 = 0.f;
    for (int jt = 0; jt < 16; jt++) {
        float a0 = 0.f, a1 = 0.f, a2 = 0.f, a3 = 0.f;
        #pragma unroll
        for (int k = 0; k < HID; k++) {
            float4 w = *(const float4*)&smem[D_DW2 + k*HID + jt*4];
            a0 = fmaf(hd[k], w.x, a0);
            a1 = fmaf(hd[k], w.y, a1);
            a2 = fmaf(hd[k], w.z, a2);
            a3 = fmaf(hd[k], w.w, a3);
        }
        float4 b = *(const float4*)&smem[D_DB2 + jt*4];
        float t0 = fmaxf(a0 + b.x, 0.0f);
        float t1 = fmaxf(a1 + b.y, 0.0f);
        float t2 = fmaxf(a2 + b.z, 0.0f);
        float t3 = fmaxf(a3 + b.w, 0.0f);
        #pragma unroll
        for (int jj = 0; jj < 4; jj++) {
            float t = (jj==0)?t0:(jj==1)?t1:(jj==2)?t2:t3;
            int j = jt*4 + jj;
            r0 = fmaf(t, smem[D_DW3 + j*FIN + 0], r0);
            r1 = fmaf(t, smem[D_DW3 + j*FIN + 1], r1);
            r2 = fmaf(t, smem[D_DW3 + j*FIN + 2], r2);
        }
    }
    r0 += smem[D_DB3+0]; r1 += smem[D_DB3+1]; r2 += smem[D_DB3+2];

    out[n*FIN + 0] = r0;
    out[n*FIN + 1] = r1;
    out[n*FIN + 2] = r2;
}

__global__ void finalize_kernel(float* out, const float* loss_ws) {
    out[NTOK*FIN] = 1.25f * loss_ws[0] * (1.0f / (float)(NTOK*EMB));
}

extern "C" void kernel_launch(void* const* d_in, const int* in_sizes, int n_in,
                              void* d_out, int out_size, void* d_ws, size_t ws_size,
                              hipStream_t stream) {
    (void)in_sizes; (void)n_in; (void)ws_size; (void)out_size;
    float* ws = (float*)d_ws;
    hipMemsetAsync(ws, 0, sizeof(float), stream);   // ws re-poisoned each call

    enc_kernel<<<NTOK/TPB, TPB, 0, stream>>>(
        (const float*)d_in[0], (const float*)d_in[1], (const float*)d_in[2],
        (const float*)d_in[3], (const float*)d_in[4], (const float*)d_in[5],
        (const float*)d_in[6], (const float*)d_in[7], (const float*)d_in[8],
        (const float*)d_in[9],
        (float*)d_out, ws);

    dec_kernel<<<NTOK/TPB, TPB, 0, stream>>>(
        (const float*)d_in[1], (const float*)d_in[2],
        (const float*)d_in[10], (const float*)d_in[11],
        (const float*)d_in[12], (const float*)d_in[13],
        (const float*)d_in[14], (const float*)d_in[15],
        (const float*)d_in[9],
        (float*)d_out);

    finalize_kernel<<<1, 1, 0, stream>>>((float*)d_out, ws);
}

// Round 5
// 316.963 us; speedup vs baseline: 11.7879x; 11.7879x over previous
//
#include <hip/hip_runtime.h>
#include <hip/hip_bf16.h>

#define BB   2048
#define SS   256
#define NTOK (BB*SS)
#define FIN  3
#define CND  4
#define EMB  4
#define HID  64
#define NC   256
#define TPB  256

// ---------------- encoder LDS layout (float offsets, float4-aligned) --------
#define E_EW1 0        // 448
#define E_EB1 448      // 64
#define E_EW2 512      // 4096
#define E_EB2 4608     // 64
#define E_EW3 4672     // 256
#define E_EB3 4928     // 4
#define E_CB  4932     // 1024 (4932*4B % 16 == 0)
#define E_CC  5956     // 256
#define E_SZ  6212     // 24848 B

// ---------------- decoder LDS layout ----------------------------------------
#define D_DW1 0        // 512
#define D_DB1 512      // 64
#define D_DW2 576      // 4096
#define D_DB2 4672     // 64
#define D_DW3 4736     // 192
#define D_DB3 4928     // 3 (pad to 4932)
#define D_CB  4932     // 1024
#define D_SZ  5956     // 23824 B

// NOTE: min-waves/EU MUST stay <=4 here. (TPB,6) caps VGPR at ~85 which
// spills h[64] to scratch -> 11.4 GB HBM traffic, 13x regression (R4).
__global__ __launch_bounds__(TPB, 4) void enc_kernel(
        const float* __restrict__ x, const float* __restrict__ mask,
        const float* __restrict__ cond,
        const float* __restrict__ ew1, const float* __restrict__ eb1,
        const float* __restrict__ ew2, const float* __restrict__ eb2,
        const float* __restrict__ ew3, const float* __restrict__ eb3,
        const float* __restrict__ cb,
        float* __restrict__ out, float* __restrict__ loss_ws) {
    __shared__ float smem[E_SZ];
    const int tid = threadIdx.x;

    for (int i = tid; i < (FIN+CND)*HID; i += TPB) smem[E_EW1+i] = ew1[i];
    for (int i = tid; i < HID;           i += TPB) smem[E_EB1+i] = eb1[i];
    for (int i = tid; i < HID*HID;       i += TPB) smem[E_EW2+i] = ew2[i];
    for (int i = tid; i < HID;           i += TPB) smem[E_EB2+i] = eb2[i];
    for (int i = tid; i < HID*EMB;       i += TPB) smem[E_EW3+i] = ew3[i];
    for (int i = tid; i < EMB;           i += TPB) smem[E_EB3+i] = eb3[i];
    for (int i = tid; i < NC*EMB;        i += TPB) smem[E_CB +i] = cb[i];
    if (tid < NC) {   // cc from GLOBAL cb (no barrier dependency)
        float c0 = cb[tid*EMB+0], c1 = cb[tid*EMB+1];
        float c2 = cb[tid*EMB+2], c3 = cb[tid*EMB+3];
        smem[E_CC+tid] = ((c0*c0 + c1*c1) + c2*c2) + c3*c3;  // validated order
    }
    __syncthreads();

    const int n  = blockIdx.x * TPB + tid;
    const int bu = n >> 8;
    const float m = mask[n];

    float cnd[CND];
    #pragma unroll
    for (int i = 0; i < CND; i++) cnd[i] = cond[bu*CND + i];

    float xin[FIN + CND];
    #pragma unroll
    for (int i = 0; i < FIN; i++) xin[i] = x[n*FIN + i] * m;
    #pragma unroll
    for (int i = 0; i < CND; i++) xin[FIN + i] = cnd[i] * m;

    // ---- encoder L1: 7 -> 64, relu (validated tree) ----
    float h1[HID];
    #pragma unroll
    for (int j = 0; j < HID; j++) {
        float a = xin[0] * smem[E_EW1 + j];
        #pragma unroll
        for (int i = 1; i < FIN+CND; i++) a = fmaf(xin[i], smem[E_EW1 + i*HID + j], a);
        a += smem[E_EB1 + j];
        h1[j] = fmaxf(a, 0.0f);
    }

    // ---- encoder L2 (relu) fused with L3 fold (validated tree) ----
    float z0 = 0.f, z1 = 0.f, z2 = 0.f, z3 = 0.f;
    for (int jt = 0; jt < 16; jt++) {
        float a0 = 0.f, a1 = 0.f, a2 = 0.f, a3 = 0.f;
        #pragma unroll
        for (int k = 0; k < HID; k++) {
            float4 w = *(const float4*)&smem[E_EW2 + k*HID + jt*4];
            a0 = fmaf(h1[k], w.x, a0);
            a1 = fmaf(h1[k], w.y, a1);
            a2 = fmaf(h1[k], w.z, a2);
            a3 = fmaf(h1[k], w.w, a3);
        }
        float4 b = *(const float4*)&smem[E_EB2 + jt*4];
        float t0 = fmaxf(a0 + b.x, 0.0f);
        float t1 = fmaxf(a1 + b.y, 0.0f);
        float t2 = fmaxf(a2 + b.z, 0.0f);
        float t3 = fmaxf(a3 + b.w, 0.0f);
        float4 w0 = *(const float4*)&smem[E_EW3 + (jt*4+0)*EMB];
        z0 = fmaf(t0, w0.x, z0); z1 = fmaf(t0, w0.y, z1);
        z2 = fmaf(t0, w0.z, z2); z3 = fmaf(t0, w0.w, z3);
        float4 w1 = *(const float4*)&smem[E_EW3 + (jt*4+1)*EMB];
        z0 = fmaf(t1, w1.x, z0); z1 = fmaf(t1, w1.y, z1);
        z2 = fmaf(t1, w1.z, z2); z3 = fmaf(t1, w1.w, z3);
        float4 w2 = *(const float4*)&smem[E_EW3 + (jt*4+2)*EMB];
        z0 = fmaf(t2, w2.x, z0); z1 = fmaf(t2, w2.y, z1);
        z2 = fmaf(t2, w2.z, z2); z3 = fmaf(t2, w2.w, z3);
        float4 w3 = *(const float4*)&smem[E_EW3 + (jt*4+3)*EMB];
        z0 = fmaf(t3, w3.x, z0); z1 = fmaf(t3, w3.y, z1);
        z2 = fmaf(t3, w3.z, z2); z3 = fmaf(t3, w3.w, z3);
    }
    z0 += smem[E_EB3+0]; z1 += smem[E_EB3+1];
    z2 += smem[E_EB3+2]; z3 += smem[E_EB3+3];

    // ---- VQ argmin (validated tree; strict < = np first-min) ----
    const float zz = ((z0*z0 + z1*z1) + z2*z2) + z3*z3;
    float best = 3.4e38f;
    int   bi   = 0;
    #pragma unroll 4
    for (int ci = 0; ci < NC; ci++) {
        float4 c = *(const float4*)&smem[E_CB + ci*EMB];
        float dot = z0 * c.x;
        dot = fmaf(z1, c.y, dot);
        dot = fmaf(z2, c.z, dot);
        dot = fmaf(z3, c.w, dot);
        float d = (zz - 2.0f*dot) + smem[E_CC + ci];
        if (d < best) { best = d; bi = ci; }
    }
    float4 q = *(const float4*)&smem[E_CB + bi*EMB];

    // ---- vq loss partial ----
    float e0 = z0-q.x, e1 = z1-q.y, e2 = z2-q.z, e3 = z3-q.w;
    float sq = ((e0*e0 + e1*e1) + e2*e2) + e3*e3;
    #pragma unroll
    for (int off = 32; off > 0; off >>= 1) sq += __shfl_down(sq, off, 64);
    if ((tid & 63) == 0) atomicAdd(loss_ws, sq);

    // idx out; decoder rereads it to recover q from its own cb copy
    out[NTOK*FIN + 1 + n] = (float)bi;
}

__global__ __launch_bounds__(TPB, 4) void dec_kernel(
        const float* __restrict__ mask, const float* __restrict__ cond,
        const float* __restrict__ dw1, const float* __restrict__ db1,
        const float* __restrict__ dw2, const float* __restrict__ db2,
        const float* __restrict__ dw3, const float* __restrict__ db3,
        const float* __restrict__ cb,
        float* __restrict__ out) {
    __shared__ float smem[D_SZ];
    const int tid = threadIdx.x;

    for (int i = tid; i < (EMB+CND)*HID; i += TPB) smem[D_DW1+i] = dw1[i];
    for (int i = tid; i < HID;           i += TPB) smem[D_DB1+i] = db1[i];
    for (int i = tid; i < HID*HID;       i += TPB) smem[D_DW2+i] = dw2[i];
    for (int i = tid; i < HID;           i += TPB) smem[D_DB2+i] = db2[i];
    for (int i = tid; i < HID*FIN;       i += TPB) smem[D_DW3+i] = dw3[i];
    for (int i = tid; i < FIN;           i += TPB) smem[D_DB3+i] = db3[i];
    for (int i = tid; i < NC*EMB;        i += TPB) smem[D_CB +i] = cb[i];
    __syncthreads();

    const int n  = blockIdx.x * TPB + tid;
    const int bu = n >> 8;
    const float m = mask[n];

    float cnd[CND];
    #pragma unroll
    for (int i = 0; i < CND; i++) cnd[i] = cond[bu*CND + i];

    const int bi = (int)out[NTOK*FIN + 1 + n];   // exact small-int roundtrip
    float4 q = *(const float4*)&smem[D_CB + bi*EMB];

    // ---- decoder L1: 8 -> 64, relu (validated tree) ----
    float zd[EMB + CND];
    zd[0] = q.x*m; zd[1] = q.y*m; zd[2] = q.z*m; zd[3] = q.w*m;
    #pragma unroll
    for (int i = 0; i < CND; i++) zd[EMB + i] = cnd[i] * m;

    float hd[HID];
    #pragma unroll
    for (int j = 0; j < HID; j++) {
        float a = zd[0] * smem[D_DW1 + j];
        #pragma unroll
        for (int i = 1; i < EMB+CND; i++) a = fmaf(zd[i], smem[D_DW1 + i*HID + j], a);
        a += smem[D_DB1 + j];
        hd[j] = fmaxf(a, 0.0f);
    }

    // ---- decoder L2 (relu) fused with L3 (validated tree) ----
    float r0 = 0.f, r1 = 0.f, r2 = 0.f;
    for (int jt = 0; jt < 16; jt++) {
        float a0 = 0.f, a1 = 0.f, a2 = 0.f, a3 = 0.f;
        #pragma unroll
        for (int k = 0; k < HID; k++) {
            float4 w = *(const float4*)&smem[D_DW2 + k*HID + jt*4];
            a0 = fmaf(hd[k], w.x, a0);
            a1 = fmaf(hd[k], w.y, a1);
            a2 = fmaf(hd[k], w.z, a2);
            a3 = fmaf(hd[k], w.w, a3);
        }
        float4 b = *(const float4*)&smem[D_DB2 + jt*4];
        float t0 = fmaxf(a0 + b.x, 0.0f);
        float t1 = fmaxf(a1 + b.y, 0.0f);
        float t2 = fmaxf(a2 + b.z, 0.0f);
        float t3 = fmaxf(a3 + b.w, 0.0f);
        #pragma unroll
        for (int jj = 0; jj < 4; jj++) {
            float t = (jj==0)?t0:(jj==1)?t1:(jj==2)?t2:t3;
            int j = jt*4 + jj;
            r0 = fmaf(t, smem[D_DW3 + j*FIN + 0], r0);
            r1 = fmaf(t, smem[D_DW3 + j*FIN + 1], r1);
            r2 = fmaf(t, smem[D_DW3 + j*FIN + 2], r2);
        }
    }
    r0 += smem[D_DB3+0]; r1 += smem[D_DB3+1]; r2 += smem[D_DB3+2];

    out[n*FIN + 0] = r0;
    out[n*FIN + 1] = r1;
    out[n*FIN + 2] = r2;
}

__global__ void finalize_kernel(float* out, const float* loss_ws) {
    out[NTOK*FIN] = 1.25f * loss_ws[0] * (1.0f / (float)(NTOK*EMB));
}

extern "C" void kernel_launch(void* const* d_in, const int* in_sizes, int n_in,
                              void* d_out, int out_size, void* d_ws, size_t ws_size,
                              hipStream_t stream) {
    (void)in_sizes; (void)n_in; (void)ws_size; (void)out_size;
    float* ws = (float*)d_ws;
    hipMemsetAsync(ws, 0, sizeof(float), stream);   // ws re-poisoned each call

    enc_kernel<<<NTOK/TPB, TPB, 0, stream>>>(
        (const float*)d_in[0], (const float*)d_in[1], (const float*)d_in[2],
        (const float*)d_in[3], (const float*)d_in[4], (const float*)d_in[5],
        (const float*)d_in[6], (const float*)d_in[7], (const float*)d_in[8],
        (const float*)d_in[9],
        (float*)d_out, ws);

    dec_kernel<<<NTOK/TPB, TPB, 0, stream>>>(
        (const float*)d_in[1], (const float*)d_in[2],
        (const float*)d_in[10], (const float*)d_in[11],
        (const float*)d_in[12], (const float*)d_in[13],
        (const float*)d_in[14], (const float*)d_in[15],
        (const float*)d_in[9],
        (float*)d_out);

    finalize_kernel<<<1, 1, 0, stream>>>((float*)d_out, ws);
}

// Round 6
// 274.126 us; speedup vs baseline: 13.6300x; 1.1563x over previous
//
#include <hip/hip_runtime.h>
#include <hip/hip_bf16.h>

#define BB   2048
#define SS   256
#define NTOK (BB*SS)
#define FIN  3
#define CND  4
#define EMB  4
#define HID  64
#define NC   256
#define TPB  256   // T=2 tokens/thread: block covers 512 tokens

// Fused LDS layout (float offsets; float4-aligned where float4-read). 44.7 KB.
#define OF_EW1 0        // 448
#define OF_EB1 448      // 64
#define OF_EW2 512      // 4096
#define OF_EB2 4608     // 64
#define OF_EW3 4672     // 256
#define OF_EB3 4928     // 4 (pad to 4944)
#define OF_CB  4944     // 1024
#define OF_CC  5968     // 256
#define OF_DW1 6224     // 512
#define OF_DB1 6736     // 64
#define OF_DW2 6800     // 4096
#define OF_DB2 10896    // 64
#define OF_DW3 10960    // 192
#define OF_DB3 11152    // 4
#define SMEM_F 11168    // 44672 B

// NOTE: min-waves/EU must stay low: this kernel needs ~160 VGPRs (2x h[64]).
// (TPB,6)-style caps spill h[] to scratch -> 11.4 GB HBM, 13x regression (R4).
__global__ __launch_bounds__(TPB, 2) void vqvae_fused(
        const float* __restrict__ x, const float* __restrict__ mask,
        const float* __restrict__ cond,
        const float* __restrict__ ew1, const float* __restrict__ eb1,
        const float* __restrict__ ew2, const float* __restrict__ eb2,
        const float* __restrict__ ew3, const float* __restrict__ eb3,
        const float* __restrict__ cb,
        const float* __restrict__ dw1, const float* __restrict__ db1,
        const float* __restrict__ dw2, const float* __restrict__ db2,
        const float* __restrict__ dw3, const float* __restrict__ db3,
        float* __restrict__ out, float* __restrict__ loss_ws) {
    __shared__ float smem[SMEM_F];
    const int tid = threadIdx.x;

    for (int i = tid; i < (FIN+CND)*HID; i += TPB) smem[OF_EW1+i] = ew1[i];
    for (int i = tid; i < HID;           i += TPB) smem[OF_EB1+i] = eb1[i];
    for (int i = tid; i < HID*HID;       i += TPB) smem[OF_EW2+i] = ew2[i];
    for (int i = tid; i < HID;           i += TPB) smem[OF_EB2+i] = eb2[i];
    for (int i = tid; i < HID*EMB;       i += TPB) smem[OF_EW3+i] = ew3[i];
    for (int i = tid; i < EMB;           i += TPB) smem[OF_EB3+i] = eb3[i];
    for (int i = tid; i < NC*EMB;        i += TPB) smem[OF_CB +i] = cb[i];
    for (int i = tid; i < (EMB+CND)*HID; i += TPB) smem[OF_DW1+i] = dw1[i];
    for (int i = tid; i < HID;           i += TPB) smem[OF_DB1+i] = db1[i];
    for (int i = tid; i < HID*HID;       i += TPB) smem[OF_DW2+i] = dw2[i];
    for (int i = tid; i < HID;           i += TPB) smem[OF_DB2+i] = db2[i];
    for (int i = tid; i < HID*FIN;       i += TPB) smem[OF_DW3+i] = dw3[i];
    for (int i = tid; i < FIN;           i += TPB) smem[OF_DB3+i] = db3[i];
    {   // cc from GLOBAL cb (no barrier dependency); tid in [0,256) covers NC
        float c0 = cb[tid*EMB+0], c1 = cb[tid*EMB+1];
        float c2 = cb[tid*EMB+2], c3 = cb[tid*EMB+3];
        smem[OF_CC+tid] = ((c0*c0 + c1*c1) + c2*c2) + c3*c3;  // validated order
    }
    __syncthreads();

    // two tokens per thread: n0 in batch 2*blk, n1 in batch 2*blk+1
    const int n0 = blockIdx.x * (2*TPB) + tid;
    const int n1 = n0 + TPB;
    const float m0 = mask[n0];
    const float m1 = mask[n1];
    const int bu0 = n0 >> 8;
    const int bu1 = bu0 + 1;

    float xin0[FIN+CND], xin1[FIN+CND];
    #pragma unroll
    for (int i = 0; i < FIN; i++) xin0[i] = x[n0*FIN + i] * m0;
    #pragma unroll
    for (int i = 0; i < FIN; i++) xin1[i] = x[n1*FIN + i] * m1;
    #pragma unroll
    for (int i = 0; i < CND; i++) xin0[FIN+i] = cond[bu0*CND + i] * m0;
    #pragma unroll
    for (int i = 0; i < CND; i++) xin1[FIN+i] = cond[bu1*CND + i] * m1;

    // ---- encoder L1: 7 -> 64, relu (validated tree; weights read once) ----
    float hA[HID], hB[HID];
    #pragma unroll
    for (int j = 0; j < HID; j++) {
        float w0 = smem[OF_EW1 + j];
        float a = xin0[0] * w0;
        float b = xin1[0] * w0;
        #pragma unroll
        for (int i = 1; i < FIN+CND; i++) {
            float wi = smem[OF_EW1 + i*HID + j];
            a = fmaf(xin0[i], wi, a);
            b = fmaf(xin1[i], wi, b);
        }
        float bias = smem[OF_EB1 + j];
        hA[j] = fmaxf(a + bias, 0.0f);
        hB[j] = fmaxf(b + bias, 0.0f);
    }

    // ---- encoder L2 (relu) fused with L3 fold (validated trees) ----
    float z0 = 0.f, z1 = 0.f, z2 = 0.f, z3 = 0.f;
    float y0 = 0.f, y1 = 0.f, y2 = 0.f, y3 = 0.f;
    for (int jt = 0; jt < 16; jt++) {
        float a0 = 0.f, a1 = 0.f, a2 = 0.f, a3 = 0.f;
        float b0 = 0.f, b1 = 0.f, b2 = 0.f, b3 = 0.f;
        #pragma unroll
        for (int k = 0; k < HID; k++) {
            float4 w = *(const float4*)&smem[OF_EW2 + k*HID + jt*4];
            a0 = fmaf(hA[k], w.x, a0);
            a1 = fmaf(hA[k], w.y, a1);
            a2 = fmaf(hA[k], w.z, a2);
            a3 = fmaf(hA[k], w.w, a3);
            b0 = fmaf(hB[k], w.x, b0);
            b1 = fmaf(hB[k], w.y, b1);
            b2 = fmaf(hB[k], w.z, b2);
            b3 = fmaf(hB[k], w.w, b3);
        }
        float4 bb = *(const float4*)&smem[OF_EB2 + jt*4];
        float ta0 = fmaxf(a0 + bb.x, 0.0f), tb0 = fmaxf(b0 + bb.x, 0.0f);
        float ta1 = fmaxf(a1 + bb.y, 0.0f), tb1 = fmaxf(b1 + bb.y, 0.0f);
        float ta2 = fmaxf(a2 + bb.z, 0.0f), tb2 = fmaxf(b2 + bb.z, 0.0f);
        float ta3 = fmaxf(a3 + bb.w, 0.0f), tb3 = fmaxf(b3 + bb.w, 0.0f);
        float4 w0 = *(const float4*)&smem[OF_EW3 + (jt*4+0)*EMB];
        z0 = fmaf(ta0, w0.x, z0); z1 = fmaf(ta0, w0.y, z1);
        z2 = fmaf(ta0, w0.z, z2); z3 = fmaf(ta0, w0.w, z3);
        y0 = fmaf(tb0, w0.x, y0); y1 = fmaf(tb0, w0.y, y1);
        y2 = fmaf(tb0, w0.z, y2); y3 = fmaf(tb0, w0.w, y3);
        float4 w1 = *(const float4*)&smem[OF_EW3 + (jt*4+1)*EMB];
        z0 = fmaf(ta1, w1.x, z0); z1 = fmaf(ta1, w1.y, z1);
        z2 = fmaf(ta1, w1.z, z2); z3 = fmaf(ta1, w1.w, z3);
        y0 = fmaf(tb1, w1.x, y0); y1 = fmaf(tb1, w1.y, y1);
        y2 = fmaf(tb1, w1.z, y2); y3 = fmaf(tb1, w1.w, y3);
        float4 w2 = *(const float4*)&smem[OF_EW3 + (jt*4+2)*EMB];
        z0 = fmaf(ta2, w2.x, z0); z1 = fmaf(ta2, w2.y, z1);
        z2 = fmaf(ta2, w2.z, z2); z3 = fmaf(ta2, w2.w, z3);
        y0 = fmaf(tb2, w2.x, y0); y1 = fmaf(tb2, w2.y, y1);
        y2 = fmaf(tb2, w2.z, y2); y3 = fmaf(tb2, w2.w, y3);
        float4 w3 = *(const float4*)&smem[OF_EW3 + (jt*4+3)*EMB];
        z0 = fmaf(ta3, w3.x, z0); z1 = fmaf(ta3, w3.y, z1);
        z2 = fmaf(ta3, w3.z, z2); z3 = fmaf(ta3, w3.w, z3);
        y0 = fmaf(tb3, w3.x, y0); y1 = fmaf(tb3, w3.y, y1);
        y2 = fmaf(tb3, w3.z, y2); y3 = fmaf(tb3, w3.w, y3);
    }
    z0 += smem[OF_EB3+0]; z1 += smem[OF_EB3+1];
    z2 += smem[OF_EB3+2]; z3 += smem[OF_EB3+3];
    y0 += smem[OF_EB3+0]; y1 += smem[OF_EB3+1];
    y2 += smem[OF_EB3+2]; y3 += smem[OF_EB3+3];

    // ---- VQ argmin both tokens (validated tree; strict < = np first-min) ----
    const float zzA = ((z0*z0 + z1*z1) + z2*z2) + z3*z3;
    const float zzB = ((y0*y0 + y1*y1) + y2*y2) + y3*y3;
    float bestA = 3.4e38f, bestB = 3.4e38f;
    int   biA = 0, biB = 0;
    #pragma unroll 4
    for (int ci = 0; ci < NC; ci++) {
        float4 c = *(const float4*)&smem[OF_CB + ci*EMB];
        float cc = smem[OF_CC + ci];
        float dotA = z0 * c.x;
        dotA = fmaf(z1, c.y, dotA);
        dotA = fmaf(z2, c.z, dotA);
        dotA = fmaf(z3, c.w, dotA);
        float dA = (zzA - 2.0f*dotA) + cc;
        if (dA < bestA) { bestA = dA; biA = ci; }
        float dotB = y0 * c.x;
        dotB = fmaf(y1, c.y, dotB);
        dotB = fmaf(y2, c.z, dotB);
        dotB = fmaf(y3, c.w, dotB);
        float dB = (zzB - 2.0f*dotB) + cc;
        if (dB < bestB) { bestB = dB; biB = ci; }
    }
    float4 qA = *(const float4*)&smem[OF_CB + biA*EMB];
    float4 qB = *(const float4*)&smem[OF_CB + biB*EMB];

    // ---- vq loss partial (atomic order arbitrary; huge threshold slack) ----
    float e0 = z0-qA.x, e1 = z1-qA.y, e2 = z2-qA.z, e3 = z3-qA.w;
    float f0 = y0-qB.x, f1 = y1-qB.y, f2 = y2-qB.z, f3 = y3-qB.w;
    float sq = (((e0*e0 + e1*e1) + e2*e2) + e3*e3)
             + (((f0*f0 + f1*f1) + f2*f2) + f3*f3);
    #pragma unroll
    for (int off = 32; off > 0; off >>= 1) sq += __shfl_down(sq, off, 64);
    if ((tid & 63) == 0) atomicAdd(loss_ws, sq);

    out[NTOK*FIN + 1 + n0] = (float)biA;
    out[NTOK*FIN + 1 + n1] = (float)biB;

    // ---- decoder input (refetch cond: frees regs over the long mid-section) ----
    float zd0[EMB+CND], zd1[EMB+CND];
    zd0[0] = qA.x*m0; zd0[1] = qA.y*m0; zd0[2] = qA.z*m0; zd0[3] = qA.w*m0;
    zd1[0] = qB.x*m1; zd1[1] = qB.y*m1; zd1[2] = qB.z*m1; zd1[3] = qB.w*m1;
    #pragma unroll
    for (int i = 0; i < CND; i++) zd0[EMB+i] = cond[bu0*CND + i] * m0;
    #pragma unroll
    for (int i = 0; i < CND; i++) zd1[EMB+i] = cond[bu1*CND + i] * m1;

    // ---- decoder L1: 8 -> 64, relu (validated tree; hA/hB reused) ----
    #pragma unroll
    for (int j = 0; j < HID; j++) {
        float w0 = smem[OF_DW1 + j];
        float a = zd0[0] * w0;
        float b = zd1[0] * w0;
        #pragma unroll
        for (int i = 1; i < EMB+CND; i++) {
            float wi = smem[OF_DW1 + i*HID + j];
            a = fmaf(zd0[i], wi, a);
            b = fmaf(zd1[i], wi, b);
        }
        float bias = smem[OF_DB1 + j];
        hA[j] = fmaxf(a + bias, 0.0f);
        hB[j] = fmaxf(b + bias, 0.0f);
    }

    // ---- decoder L2 (relu) fused with L3 (validated trees) ----
    float r0 = 0.f, r1 = 0.f, r2 = 0.f;
    float s0 = 0.f, s1 = 0.f, s2 = 0.f;
    for (int jt = 0; jt < 16; jt++) {
        float a0 = 0.f, a1 = 0.f, a2 = 0.f, a3 = 0.f;
        float b0 = 0.f, b1 = 0.f, b2 = 0.f, b3 = 0.f;
        #pragma unroll
        for (int k = 0; k < HID; k++) {
            float4 w = *(const float4*)&smem[OF_DW2 + k*HID + jt*4];
            a0 = fmaf(hA[k], w.x, a0);
            a1 = fmaf(hA[k], w.y, a1);
            a2 = fmaf(hA[k], w.z, a2);
            a3 = fmaf(hA[k], w.w, a3);
            b0 = fmaf(hB[k], w.x, b0);
            b1 = fmaf(hB[k], w.y, b1);
            b2 = fmaf(hB[k], w.z, b2);
            b3 = fmaf(hB[k], w.w, b3);
        }
        float4 bb = *(const float4*)&smem[OF_DB2 + jt*4];
        float ta0 = fmaxf(a0 + bb.x, 0.0f), tb0 = fmaxf(b0 + bb.x, 0.0f);
        float ta1 = fmaxf(a1 + bb.y, 0.0f), tb1 = fmaxf(b1 + bb.y, 0.0f);
        float ta2 = fmaxf(a2 + bb.z, 0.0f), tb2 = fmaxf(b2 + bb.z, 0.0f);
        float ta3 = fmaxf(a3 + bb.w, 0.0f), tb3 = fmaxf(b3 + bb.w, 0.0f);
        #pragma unroll
        for (int jj = 0; jj < 4; jj++) {
            float ta = (jj==0)?ta0:(jj==1)?ta1:(jj==2)?ta2:ta3;
            float tb = (jj==0)?tb0:(jj==1)?tb1:(jj==2)?tb2:tb3;
            int j = jt*4 + jj;
            float w0 = smem[OF_DW3 + j*FIN + 0];
            float w1 = smem[OF_DW3 + j*FIN + 1];
            float w2 = smem[OF_DW3 + j*FIN + 2];
            r0 = fmaf(ta, w0, r0); s0 = fmaf(tb, w0, s0);
            r1 = fmaf(ta, w1, r1); s1 = fmaf(tb, w1, s1);
            r2 = fmaf(ta, w2, r2); s2 = fmaf(tb, w2, s2);
        }
    }
    r0 += smem[OF_DB3+0]; r1 += smem[OF_DB3+1]; r2 += smem[OF_DB3+2];
    s0 += smem[OF_DB3+0]; s1 += smem[OF_DB3+1]; s2 += smem[OF_DB3+2];

    out[n0*FIN + 0] = r0;
    out[n0*FIN + 1] = r1;
    out[n0*FIN + 2] = r2;
    out[n1*FIN + 0] = s0;
    out[n1*FIN + 1] = s1;
    out[n1*FIN + 2] = s2;
}

__global__ void finalize_kernel(float* out, const float* loss_ws) {
    out[NTOK*FIN] = 1.25f * loss_ws[0] * (1.0f / (float)(NTOK*EMB));
}

extern "C" void kernel_launch(void* const* d_in, const int* in_sizes, int n_in,
                              void* d_out, int out_size, void* d_ws, size_t ws_size,
                              hipStream_t stream) {
    (void)in_sizes; (void)n_in; (void)ws_size; (void)out_size;
    float* ws = (float*)d_ws;
    hipMemsetAsync(ws, 0, sizeof(float), stream);   // ws re-poisoned each call

    vqvae_fused<<<NTOK/(2*TPB), TPB, 0, stream>>>(
        (const float*)d_in[0], (const float*)d_in[1], (const float*)d_in[2],
        (const float*)d_in[3], (const float*)d_in[4], (const float*)d_in[5],
        (const float*)d_in[6], (const float*)d_in[7], (const float*)d_in[8],
        (const float*)d_in[9], (const float*)d_in[10], (const float*)d_in[11],
        (const float*)d_in[12], (const float*)d_in[13], (const float*)d_in[14],
        (const float*)d_in[15],
        (float*)d_out, ws);

    finalize_kernel<<<1, 1, 0, stream>>>((float*)d_out, ws);
}